// Round 2
// baseline (104.689 us; speedup 1.0000x reference)
//
#include <hip/hip_runtime.h>
#include <math.h>

// CapsShapeLayer: B=256, D=10, M=32, P=36, I=8, O=16, 3 routing iters
#define BB 256
#define DD 10
#define MM 32
#define PP 36
#define II 8
#define OO 16
#define NT 512            // 8 waves/block -> 2 waves/SIMD (was 1)
#define BS (DD*MM + 1)    // 321: b_l p-major stride; bank = (p+m)%32 -> conflict-free
#define LS (PP + 1)       // 37: lse row stride; bank = (5m+p)%32, gcd(5,32)=1 -> conflict-free

__device__ __forceinline__ float dot8(const float4 a0, const float4 a1,
                                      const float4 b0, const float4 b1) {
    return a0.x*b0.x + a0.y*b0.y + a0.z*b0.z + a0.w*b0.w
         + a1.x*b1.x + a1.y*b1.y + a1.z*b1.z + a1.w*b1.w;
}

// s-partials: thread t<320 handles (d, o, m-half), 16 m's each.
// ystride_d = 0 for the d-independent ybar, MM*II for per-d y rows.
__device__ __forceinline__ void s_stage(const float* __restrict__ W,
                                        const float* __restrict__ ybase,
                                        int ystride_d, float* spart, int tid)
{
    if (tid < DD*OO*2) {
        const int d  = tid >> 5;
        const int o  = (tid & 31) >> 1;
        const int mh = tid & 1;
        const float* yb = ybase + d * ystride_d;
        float acc = 0.f;
        #pragma unroll
        for (int j = 0; j < 16; ++j) {
            const int m = (mh << 4) + j;
            const float4* wp = (const float4*)(W + ((size_t)((d*MM + m)*OO + o)) * II);
            const float4* yp = (const float4*)(yb + m*II);
            acc += dot8(wp[0], wp[1], yp[0], yp[1]);
        }
        spart[tid] = acc;
    }
}

__global__ void __launch_bounds__(NT, 2) caps_routing(
    const float* __restrict__ x,   // (B, M, P, I)
    const float* __restrict__ W,   // (D, M, O, I)
    float* __restrict__ out)       // (B, D, O)
{
    const int bidx = blockIdx.x;
    const int tid  = threadIdx.x;
    const float* __restrict__ xb = x + (size_t)bidx * (MM*PP*II);

    __shared__ __align__(16) float b_l [PP*BS];     // 46224 B, p-major logits
    __shared__ __align__(16) float lse [MM*LS];     //  4736 B
    __shared__ __align__(16) float yz  [DD*MM*II];  // 10240 B  y / z scratch
    __shared__ __align__(16) float ybar[MM*II];     //  1024 B
    __shared__ __align__(16) float spart[DD*OO*2];  //  1280 B
    __shared__ __align__(16) float s_l [DD*OO];     //   640 B
    __shared__ __align__(16) float v_l [DD*OO];     //   640 B
    // total 64784 B <= 64 KB/WG

    // ========== iter 1: b==0 -> c = 1/D exactly; ybar[m,i] = 0.1 * sum_p x ==========
    if (tid < MM*II) {
        const int m = tid >> 3, i = tid & 7;
        float acc = 0.f;
        #pragma unroll 6
        for (int p = 0; p < PP; ++p) acc += xb[(m*PP + p)*II + i];
        ybar[tid] = 0.1f * acc;
    }
    __syncthreads();

    s_stage(W, ybar, 0, spart, tid);                 // s1 partials
    __syncthreads();
    if (tid < DD*OO) s_l[tid] = spart[2*tid] + spart[2*tid + 1];
    __syncthreads();
    if (tid < DD*OO) {                               // v1 = squash(s1)
        const int d = tid >> 4;
        float sq = 0.f;
        #pragma unroll
        for (int o2 = 0; o2 < OO; ++o2) { const float t = s_l[d*OO + o2]; sq += t*t; }
        v_l[tid] = (sq / (1.f + sq)) * (s_l[tid] / sqrtf(sq + 1e-7f));
    }
    __syncthreads();

    // z1[d,m,i] = sum_o W[d,m,o,i] * v1[d,o]
    for (int slot = tid; slot < DD*MM*II; slot += NT) {
        const int d = slot >> 8, mi = slot & 255;
        const int m = mi >> 3, i = mi & 7;
        const float* wp = W + ((size_t)(d*MM + m)*OO) * II + i;
        const float* vp = v_l + d*OO;
        float acc = 0.f;
        #pragma unroll
        for (int o = 0; o < OO; ++o) acc += wp[o*II] * vp[o];
        yz[slot] = acc;
    }
    __syncthreads();

    // b1[d,m,p] = x[m,p,:].z1[d,m,:]   (p-major store, conflict-free)
    for (int s = tid; s < DD*MM*PP; s += NT) {
        const int d = s / (MM*PP);
        const int r = s - d*(MM*PP);
        const int m = r / PP;
        const int p = r - m*PP;
        const float4* xp = (const float4*)(xb + (size_t)(m*PP + p)*II);
        const float4* zp = (const float4*)(yz + (size_t)(d*MM + m)*II);
        b_l[p*BS + d*MM + m] = dot8(xp[0], xp[1], zp[0], zp[1]);
    }
    __syncthreads();

    // ========== iter 2: softmax over d ==========
    for (int mp = tid; mp < MM*PP; mp += NT) {
        const int m = mp / PP, p = mp - m*PP;
        const float* bp = b_l + p*BS + m;            // d-stride = MM
        float mx = bp[0];
        #pragma unroll
        for (int d = 1; d < DD; ++d) mx = fmaxf(mx, bp[d*MM]);
        float sum = 0.f;
        #pragma unroll
        for (int d = 0; d < DD; ++d) sum += __expf(bp[d*MM] - mx);
        lse[m*LS + p] = mx + __logf(sum);
    }
    __syncthreads();

    // y2[d,m,:] = sum_p exp(b - lse) * x[m,p,:]
    if (tid < DD*MM) {
        const int d = tid >> 5, m = tid & 31;
        const float* bcol = b_l + d*MM + m;          // p-stride = BS
        const float* lp   = lse + m*LS;
        float a0=0.f,a1=0.f,a2=0.f,a3=0.f,a4=0.f,a5=0.f,a6=0.f,a7=0.f;
        #pragma unroll 6
        for (int p = 0; p < PP; ++p) {
            const float c = __expf(bcol[p*BS] - lp[p]);
            const float4* xp = (const float4*)(xb + (size_t)(m*PP + p)*II);
            const float4 u0 = xp[0], u1 = xp[1];
            a0 += c*u0.x; a1 += c*u0.y; a2 += c*u0.z; a3 += c*u0.w;
            a4 += c*u1.x; a5 += c*u1.y; a6 += c*u1.z; a7 += c*u1.w;
        }
        float4* yo = (float4*)(yz + (size_t)tid * II);
        yo[0] = make_float4(a0,a1,a2,a3);
        yo[1] = make_float4(a4,a5,a6,a7);
    }
    __syncthreads();

    s_stage(W, yz, MM*II, spart, tid);               // s2 partials
    __syncthreads();
    if (tid < DD*OO) s_l[tid] = spart[2*tid] + spart[2*tid + 1];
    __syncthreads();
    if (tid < DD*OO) {                               // v2 = squash(s2)
        const int d = tid >> 4;
        float sq = 0.f;
        #pragma unroll
        for (int o2 = 0; o2 < OO; ++o2) { const float t = s_l[d*OO + o2]; sq += t*t; }
        v_l[tid] = (sq / (1.f + sq)) * (s_l[tid] / sqrtf(sq + 1e-7f));
    }
    __syncthreads();

    // z2 (overwrite yz)
    for (int slot = tid; slot < DD*MM*II; slot += NT) {
        const int d = slot >> 8, mi = slot & 255;
        const int m = mi >> 3, i = mi & 7;
        const float* wp = W + ((size_t)(d*MM + m)*OO) * II + i;
        const float* vp = v_l + d*OO;
        float acc = 0.f;
        #pragma unroll
        for (int o = 0; o < OO; ++o) acc += wp[o*II] * vp[o];
        yz[slot] = acc;
    }
    __syncthreads();

    // b2 = b1 + x.z2
    for (int s = tid; s < DD*MM*PP; s += NT) {
        const int d = s / (MM*PP);
        const int r = s - d*(MM*PP);
        const int m = r / PP;
        const int p = r - m*PP;
        const float4* xp = (const float4*)(xb + (size_t)(m*PP + p)*II);
        const float4* zp = (const float4*)(yz + (size_t)(d*MM + m)*II);
        b_l[p*BS + d*MM + m] += dot8(xp[0], xp[1], zp[0], zp[1]);
    }
    __syncthreads();

    // ========== final: softmax over P (axis=3), logits in registers ==========
    if (tid < DD*MM) {
        const int d = tid >> 5, m = tid & 31;
        const float* bcol = b_l + d*MM + m;
        float e[PP];
        #pragma unroll
        for (int p = 0; p < PP; ++p) e[p] = bcol[p*BS];
        float mx = e[0];
        #pragma unroll
        for (int p = 1; p < PP; ++p) mx = fmaxf(mx, e[p]);
        float sum = 0.f;
        #pragma unroll
        for (int p = 0; p < PP; ++p) { e[p] = __expf(e[p] - mx); sum += e[p]; }
        const float rs = 1.f / sum;
        float a0=0.f,a1=0.f,a2=0.f,a3=0.f,a4=0.f,a5=0.f,a6=0.f,a7=0.f;
        #pragma unroll 6
        for (int p = 0; p < PP; ++p) {
            const float c = e[p] * rs;
            const float4* xp = (const float4*)(xb + (size_t)(m*PP + p)*II);
            const float4 u0 = xp[0], u1 = xp[1];
            a0 += c*u0.x; a1 += c*u0.y; a2 += c*u0.z; a3 += c*u0.w;
            a4 += c*u1.x; a5 += c*u1.y; a6 += c*u1.z; a7 += c*u1.w;
        }
        float4* yo = (float4*)(yz + (size_t)tid * II);
        yo[0] = make_float4(a0,a1,a2,a3);
        yo[1] = make_float4(a4,a5,a6,a7);
    }
    __syncthreads();

    s_stage(W, yz, MM*II, spart, tid);               // s3 partials
    __syncthreads();
    if (tid < DD*OO) s_l[tid] = spart[2*tid] + spart[2*tid + 1];
    __syncthreads();
    if (tid < DD*OO) {                               // out = squash(s3)
        const int d = tid >> 4;
        float sq = 0.f;
        #pragma unroll
        for (int o2 = 0; o2 < OO; ++o2) { const float t = s_l[d*OO + o2]; sq += t*t; }
        out[(size_t)bidx * (DD*OO) + tid] =
            (sq / (1.f + sq)) * (s_l[tid] / sqrtf(sq + 1e-7f));
    }
}

extern "C" void kernel_launch(void* const* d_in, const int* in_sizes, int n_in,
                              void* d_out, int out_size, void* d_ws, size_t ws_size,
                              hipStream_t stream) {
    (void)in_sizes; (void)n_in; (void)out_size; (void)d_ws; (void)ws_size;
    const float* x = (const float*)d_in[0];  // (B, M, P, I)
    const float* W = (const float*)d_in[1];  // (1, D, M, 1, O, I)
    float* out = (float*)d_out;              // (B, D, O)
    caps_routing<<<dim3(BB), dim3(NT), 0, stream>>>(x, W, out);
}

// Round 3
// 95.047 us; speedup vs baseline: 1.1014x; 1.1014x over previous
//
#include <hip/hip_runtime.h>
#include <math.h>

// CapsShapeLayer: B=256, D=10, M=32, P=36, I=8, O=16, 3 routing iters
#define BB 256
#define DD 10
#define MM 32
#define PP 36
#define II 8
#define OO 16
#define NT 640        // 10 waves/block, grid=256 -> 1 block/CU
#define XS 292        // x_lds per-m stride (288+4): spreads b128 chunks across bank quads
#define RS 37         // rsum row stride: bank = (5m+p)%32, gcd(5,32)=1 -> conflict-free

__device__ __forceinline__ float dot8(const float4 a0, const float4 a1,
                                      const float4 b0, const float4 b1) {
    return a0.x*b0.x + a0.y*b0.y + a0.z*b0.z + a0.w*b0.w
         + a1.x*b1.x + a1.y*b1.y + a1.z*b1.z + a1.w*b1.w;
}

// s[d,o] partials: thread t<320 = (d, o, m-half), 16 m's each.
// WEIGHTED: per-m factor 1/wsum[d,m] (final-iter softmax normalization).
template<bool WEIGHTED>
__device__ __forceinline__ void s_partials(const float* __restrict__ W,
                                           const float* __restrict__ ybase, int ystride,
                                           const float* __restrict__ wsum,
                                           float* __restrict__ sp, int tid)
{
    if (tid < DD*OO*2) {
        const int d  = tid >> 5;
        const int o  = (tid & 31) >> 1;
        const int mh = tid & 1;
        float acc = 0.f;
        #pragma unroll
        for (int j = 0; j < 16; ++j) {
            const int m = (mh << 4) + j;
            const float4* wp = (const float4*)(W + ((size_t)((d*MM + m)*OO + o)) * II);
            const float4* yp = (const float4*)(ybase + d*ystride + m*II);
            float t = dot8(wp[0], wp[1], yp[0], yp[1]);
            if (WEIGHTED) t *= 1.0f / wsum[d*MM + m];
            acc += t;
        }
        sp[tid] = acc;
    }
}

// tid<160: s = sp[2t]+sp[2t+1]; squash over the 16-lane o-group via shuffles.
__device__ __forceinline__ float combine_squash(const float* __restrict__ sp, int tid)
{
    const float sv = sp[2*tid] + sp[2*tid + 1];
    float sq = sv * sv;
    sq += __shfl_xor(sq, 1, 64);
    sq += __shfl_xor(sq, 2, 64);
    sq += __shfl_xor(sq, 4, 64);
    sq += __shfl_xor(sq, 8, 64);
    return (sq / (1.f + sq)) * (sv / sqrtf(sq + 1e-7f));
}

__global__ void __launch_bounds__(NT) caps_routing(
    const float* __restrict__ x,   // (B, M, P, I)
    const float* __restrict__ W,   // (D, M, O, I)
    float* __restrict__ out)       // (B, D, O)
{
    const int bidx = blockIdx.x;
    const int tid  = threadIdx.x;
    const float* __restrict__ xb = x + (size_t)bidx * (MM*PP*II);

    // b is never stored: b = x . z_acc (linear in z), recomputed on demand.
    __shared__ __align__(16) float xs [MM*XS];     // 37376 B  x staged once
    __shared__ __align__(16) float z  [DD*MM*II];  // 10240 B  z accumulator (z1, then z1+z2)
    __shared__ __align__(16) float rsp[MM*RS];     //  4736 B  rsum(m,p) / s-partials alias
    __shared__ __align__(16) float y  [DD*MM*II];  // 10240 B  y scratch (ybar aliases [0:256])
    __shared__ __align__(16) float sumdm[DD*MM];   //  1280 B  final per-(d,m) exp sums
    __shared__ __align__(16) float v_l[DD*OO];     //   640 B
    // total 64512 B <= 64 KB

    // ---- 1: stage x -> LDS (padded rows, coalesced float4) ----
    {
        const float4* xg = (const float4*)xb;
        for (int t = tid; t < MM*72; t += NT) {          // 72 float4 per m-row
            const int m = t / 72, r = t - m*72;
            *(float4*)(xs + m*XS + 4*r) = xg[t];
        }
    }
    __syncthreads();

    // ---- 2: iter1: c = 1/D exactly -> ybar[m,i] = 0.1 * sum_p x (alias y[0:256]) ----
    if (tid < MM*II) {
        const int m = tid >> 3, i = tid & 7;
        const float* xr = xs + m*XS + i;
        float acc = 0.f;
        #pragma unroll
        for (int p = 0; p < PP; ++p) acc += xr[p*II];
        y[tid] = 0.1f * acc;
    }
    __syncthreads();

    // ---- 3: s1 partials ----
    s_partials<false>(W, y, 0, nullptr, rsp, tid);
    __syncthreads();
    // ---- 4: v1 = squash(s1) ----
    if (tid < DD*OO) v_l[tid] = combine_squash(rsp, tid);
    __syncthreads();

    // ---- 5: z1[d,m,i] = sum_o W[d,m,o,i] * v1[d,o] ----
    for (int s = tid; s < DD*MM*II; s += NT) {
        const int d = s >> 8, mi = s & 255;
        const int m = mi >> 3, i = mi & 7;
        const float* wp = W + ((size_t)(d*MM + m)*OO) * II + i;
        const float* vp = v_l + d*OO;
        float acc = 0.f;
        #pragma unroll
        for (int o = 0; o < OO; ++o) acc += wp[o*II] * vp[o];
        z[s] = acc;
    }
    __syncthreads();

    // ---- 6: rsum[m,p] = 1/sum_d exp(b1)   (b1 = x.z1 on the fly; |b| small -> no max) ----
    for (int t = tid; t < MM*PP; t += NT) {
        const int m = t / PP, p = t - m*PP;
        const float4* xp = (const float4*)(xs + m*XS + p*II);
        const float4 x0 = xp[0], x1 = xp[1];
        float se = 0.f;
        #pragma unroll
        for (int d = 0; d < DD; ++d) {
            const float4* zp = (const float4*)(z + (d*MM + m)*II);
            se += __expf(dot8(x0, x1, zp[0], zp[1]));
        }
        rsp[m*RS + p] = 1.0f / se;
    }
    for (int s = tid; s < DD*MM*II; s += NT) y[s] = 0.f;  // zero y for atomics
    __syncthreads();

    // ---- 7: y2[d,m,:] = sum_p exp(b1)*rsum * x   (p split in halves, LDS atomic combine) ----
    {
        const int dm = tid >> 1, ph = tid & 1;
        const int m  = dm & 31;
        const float4* zp = (const float4*)(z + dm*II);
        const float4 z0 = zp[0], z1v = zp[1];
        const float* xr = xs + m*XS;
        const float* rr = rsp + m*RS;
        float a0=0.f,a1=0.f,a2=0.f,a3=0.f,a4=0.f,a5=0.f,a6=0.f,a7=0.f;
        const int p0 = ph * (PP/2);
        #pragma unroll
        for (int q = 0; q < PP/2; ++q) {
            const int p = p0 + q;
            const float4* xp = (const float4*)(xr + p*II);
            const float4 x0 = xp[0], x1 = xp[1];
            const float e = __expf(dot8(x0, x1, z0, z1v)) * rr[p];
            a0 += e*x0.x; a1 += e*x0.y; a2 += e*x0.z; a3 += e*x0.w;
            a4 += e*x1.x; a5 += e*x1.y; a6 += e*x1.z; a7 += e*x1.w;
        }
        float* yp = y + dm*II;
        atomicAdd(yp+0,a0); atomicAdd(yp+1,a1); atomicAdd(yp+2,a2); atomicAdd(yp+3,a3);
        atomicAdd(yp+4,a4); atomicAdd(yp+5,a5); atomicAdd(yp+6,a6); atomicAdd(yp+7,a7);
    }
    __syncthreads();

    // ---- 8: s2 partials ----
    s_partials<false>(W, y, MM*II, nullptr, rsp, tid);
    __syncthreads();
    // ---- 9a: v2 ----
    if (tid < DD*OO) v_l[tid] = combine_squash(rsp, tid);
    __syncthreads();

    // ---- 9: z_acc += z2; zero y and sumdm for final stage ----
    for (int s = tid; s < DD*MM*II; s += NT) {
        const int d = s >> 8, mi = s & 255;
        const int m = mi >> 3, i = mi & 7;
        const float* wp = W + ((size_t)(d*MM + m)*OO) * II + i;
        const float* vp = v_l + d*OO;
        float acc = 0.f;
        #pragma unroll
        for (int o = 0; o < OO; ++o) acc += wp[o*II] * vp[o];
        z[s] += acc;          // z_acc = z1 + z2  ->  b2 = x . z_acc
        y[s] = 0.f;
    }
    if (tid < DD*MM) sumdm[tid] = 0.f;
    __syncthreads();

    // ---- 10: final softmax over P: y3 += exp(b2)*x, sumdm += exp(b2) ----
    {
        const int dm = tid >> 1, ph = tid & 1;
        const int m  = dm & 31;
        const float4* zp = (const float4*)(z + dm*II);
        const float4 z0 = zp[0], z1v = zp[1];
        const float* xr = xs + m*XS;
        float se = 0.f;
        float a0=0.f,a1=0.f,a2=0.f,a3=0.f,a4=0.f,a5=0.f,a6=0.f,a7=0.f;
        const int p0 = ph * (PP/2);
        #pragma unroll
        for (int q = 0; q < PP/2; ++q) {
            const int p = p0 + q;
            const float4* xp = (const float4*)(xr + p*II);
            const float4 x0 = xp[0], x1 = xp[1];
            const float e = __expf(dot8(x0, x1, z0, z1v));
            se += e;
            a0 += e*x0.x; a1 += e*x0.y; a2 += e*x0.z; a3 += e*x0.w;
            a4 += e*x1.x; a5 += e*x1.y; a6 += e*x1.z; a7 += e*x1.w;
        }
        float* yp = y + dm*II;
        atomicAdd(yp+0,a0); atomicAdd(yp+1,a1); atomicAdd(yp+2,a2); atomicAdd(yp+3,a3);
        atomicAdd(yp+4,a4); atomicAdd(yp+5,a5); atomicAdd(yp+6,a6); atomicAdd(yp+7,a7);
        atomicAdd(&sumdm[dm], se);
    }
    __syncthreads();

    // ---- 11: s3 partials with per-(d,m) 1/sumdm weighting ----
    s_partials<true>(W, y, MM*II, sumdm, rsp, tid);
    __syncthreads();

    // ---- 12: out = squash(s3) ----
    if (tid < DD*OO)
        out[(size_t)bidx * (DD*OO) + tid] = combine_squash(rsp, tid);
}

extern "C" void kernel_launch(void* const* d_in, const int* in_sizes, int n_in,
                              void* d_out, int out_size, void* d_ws, size_t ws_size,
                              hipStream_t stream) {
    (void)in_sizes; (void)n_in; (void)out_size; (void)d_ws; (void)ws_size;
    const float* x = (const float*)d_in[0];  // (B, M, P, I)
    const float* W = (const float*)d_in[1];  // (1, D, M, 1, O, I)
    float* out = (float*)d_out;              // (B, D, O)
    caps_routing<<<dim3(BB), dim3(NT), 0, stream>>>(x, W, out);
}